// Round 4
// baseline (523.942 us; speedup 1.0000x reference)
//
#include <hip/hip_runtime.h>
#include <hip/hip_bf16.h>

// PINNLayer — NN=100000 nodes, NE=3200000 edges.
// Inputs fp32/int32; OUTPUT IS FP32 (round-3 forensics: identical absmax
// 100370.875 across two kernels = fp32 word 0x47C4xxxx built from packed
// bf16 [src,dst] pair read as float — the harness reads d_out as float*).
// d_out fp32 layout: [ result (NN) | out2 (NE,3) rows = [src,dst,val] ].
//
// val[e] = b + sum_{j<36} flow_flat[e*12+j] * w_re[j],
//   w_re[kh*12 + kw*4 + i] = conv_w[i*9 + kh*3 + kw]

__device__ __forceinline__ float conv_val(const float* __restrict__ flow,
                                          long long e, const float* w) {
    const float4* fp = (const float4*)(flow + e * 12);
    float acc = w[36];
#pragma unroll
    for (int q = 0; q < 9; ++q) {
        float4 v = fp[q];
        acc = fmaf(v.x, w[q * 4 + 0], acc);
        acc = fmaf(v.y, w[q * 4 + 1], acc);
        acc = fmaf(v.z, w[q * 4 + 2], acc);
        acc = fmaf(v.w, w[q * 4 + 3], acc);
    }
    return acc;
}

__device__ __forceinline__ void load_w(const float* __restrict__ conv_w,
                                       const float* __restrict__ conv_b,
                                       float* w) {
    int t = threadIdx.x;
    if (t < 36) {
        int i  = t & 3;
        int kw = (t >> 2) % 3;
        int kh = t / 12;
        w[t] = conv_w[i * 9 + kh * 3 + kw];
    }
    if (t == 36) w[36] = conv_b[0];
    __syncthreads();
}

// ---------------- Path A (workspace big enough) ----------------

__global__ __launch_bounds__(256) void node_prep(
    const float* __restrict__ od,
    float* __restrict__ conc, float* __restrict__ inv_size,
    float* __restrict__ exh,  float* __restrict__ node_new, int n_nodes)
{
    int n = blockIdx.x * blockDim.x + threadIdx.x;
    if (n >= n_nodes) return;
    long long b = (long long)n * 48 + 45;   // origin_data[n,15,:]
    float c  = od[b + 0];
    float p  = od[b + 1];
    float is = 1.0f / od[b + 2];
    conc[n] = c; inv_size[n] = is;
    exh[n] = 0.0052f * p * is;
    node_new[n] = 0.0f;
}

__global__ __launch_bounds__(256) void edge_full(
    const float* __restrict__ flow, const int* __restrict__ ei,
    const float* __restrict__ conv_w, const float* __restrict__ conv_b,
    const float* __restrict__ conc, const float* __restrict__ inv_size,
    float* __restrict__ node_new, float* __restrict__ out2, int n_edges)
{
    __shared__ float w[40];
    load_w(conv_w, conv_b, w);
    int e = blockIdx.x * blockDim.x + threadIdx.x;
    if (e >= n_edges) return;

    float acc = conv_val(flow, e, w);
    int s = ei[e];
    int d = ei[n_edges + e];

    float* o = out2 + (long long)e * 3;
    o[0] = (float)s; o[1] = (float)d; o[2] = acc;

    if (s != d) {
        float msg = acc * conc[s];
        atomicAdd(node_new + s, -msg * inv_size[s]);
        atomicAdd(node_new + d,  msg * inv_size[d]);
    }
}

__global__ __launch_bounds__(256) void node_final_a(
    const float* __restrict__ conc, const float* __restrict__ exh,
    const float* __restrict__ node_new, float* __restrict__ out, int n_nodes)
{
    int n = blockIdx.x * blockDim.x + threadIdx.x;
    if (n >= n_nodes) return;
    float r = conc[n];
    if (n != n_nodes - 1) r += node_new[n] + exh[n];
    out[n] = r;
}

// ---------------- Path B (no workspace: scratch in d_out tail) ----------------

__global__ __launch_bounds__(256) void zero_acc(float* __restrict__ a, int n) {
    int i = blockIdx.x * blockDim.x + threadIdx.x;
    if (i < n) a[i] = 0.0f;
}

__global__ __launch_bounds__(256) void edge_main_b(
    const float* __restrict__ flow, const int* __restrict__ ei,
    const float* __restrict__ conv_w, const float* __restrict__ conv_b,
    const float* __restrict__ od, float* __restrict__ node_new,
    float* __restrict__ out2, int n_edges, int e_cut)
{
    __shared__ float w[40];
    load_w(conv_w, conv_b, w);
    int e = blockIdx.x * blockDim.x + threadIdx.x;
    if (e >= n_edges) return;

    float acc = conv_val(flow, e, w);
    int s = ei[e];
    int d = ei[n_edges + e];

    if (e < e_cut) {
        float* o = out2 + (long long)e * 3;
        o[0] = (float)s; o[1] = (float)d; o[2] = acc;
    }
    if (s != d) {
        float msg = acc * od[(long long)s * 48 + 45];
        atomicAdd(node_new + s, -msg / od[(long long)s * 48 + 47]);
        atomicAdd(node_new + d,  msg / od[(long long)d * 48 + 47]);
    }
}

__global__ __launch_bounds__(256) void node_final_b(
    const float* __restrict__ od, const float* __restrict__ node_new,
    float* __restrict__ out, int n_nodes)
{
    int n = blockIdx.x * blockDim.x + threadIdx.x;
    if (n >= n_nodes) return;
    long long b = (long long)n * 48 + 45;
    float r = od[b + 0];
    if (n != n_nodes - 1) r += node_new[n] + 0.0052f * od[b + 1] / od[b + 2];
    out[n] = r;
}

__global__ __launch_bounds__(256) void edge_tail_b(
    const float* __restrict__ flow, const int* __restrict__ ei,
    const float* __restrict__ conv_w, const float* __restrict__ conv_b,
    float* __restrict__ out2, int n_edges, int e_cut, int n_tail)
{
    __shared__ float w[40];
    load_w(conv_w, conv_b, w);
    int i = blockIdx.x * blockDim.x + threadIdx.x;
    if (i >= n_tail) return;
    long long e = (long long)e_cut + i;
    float acc = conv_val(flow, e, w);
    float* o = out2 + e * 3;
    o[0] = (float)ei[e]; o[1] = (float)ei[n_edges + e]; o[2] = acc;
}

extern "C" void kernel_launch(void* const* d_in, const int* in_sizes, int n_in,
                              void* d_out, int out_size, void* d_ws, size_t ws_size,
                              hipStream_t stream) {
    const float* od   = (const float*)d_in[0];
    const float* flow = (const float*)d_in[1];
    const float* cw   = (const float*)d_in[2];
    const float* cb   = (const float*)d_in[3];
    const int*   ei   = (const int*)d_in[4];

    const int n_nodes = in_sizes[0] / 48;
    const int n_edges = in_sizes[4] / 2;

    float* out_res = (float*)d_out;          // (NN,)
    float* out2    = out_res + n_nodes;      // (NE,3)

    dim3 blk(256);
    dim3 grid_nodes((n_nodes + 255) / 256);
    dim3 grid_edges((n_edges + 255) / 256);

    if (ws_size >= (size_t)4 * n_nodes * sizeof(float)) {
        // Path A: compact node arrays + accumulator in d_ws.
        float* ws       = (float*)d_ws;
        float* conc     = ws;
        float* inv_size = ws + (size_t)n_nodes;
        float* exh      = ws + 2 * (size_t)n_nodes;
        float* node_new = ws + 3 * (size_t)n_nodes;

        node_prep<<<grid_nodes, blk, 0, stream>>>(od, conc, inv_size, exh,
                                                  node_new, n_nodes);
        edge_full<<<grid_edges, blk, 0, stream>>>(flow, ei, cw, cb, conc,
                                                  inv_size, node_new, out2,
                                                  n_edges);
        node_final_a<<<grid_nodes, blk, 0, stream>>>(conc, exh, node_new,
                                                     out_res, n_nodes);
    } else {
        // Path B: accumulator = last n_nodes floats of d_out; defer the out2
        // rows that overlap it, write them after node_final consumes scratch.
        float* node_new = out_res + (long long)out_size - n_nodes;
        const long long S = (long long)out_size - 2LL * n_nodes; // out2-local
        const int e_cut  = (int)(S / 3);   // ceil((S-2)/3)
        const int n_tail = n_edges - e_cut;

        zero_acc<<<grid_nodes, blk, 0, stream>>>(node_new, n_nodes);
        edge_main_b<<<grid_edges, blk, 0, stream>>>(flow, ei, cw, cb, od,
                                                    node_new, out2, n_edges,
                                                    e_cut);
        node_final_b<<<grid_nodes, blk, 0, stream>>>(od, node_new, out_res,
                                                     n_nodes);
        if (n_tail > 0) {
            dim3 grid_tail((n_tail + 255) / 256);
            edge_tail_b<<<grid_tail, blk, 0, stream>>>(flow, ei, cw, cb, out2,
                                                       n_edges, e_cut, n_tail);
        }
    }
}

// Round 5
// 511.156 us; speedup vs baseline: 1.0250x; 1.0250x over previous
//
#include <hip/hip_runtime.h>
#include <hip/hip_bf16.h>

// PINNLayer — NN=100000 nodes, NE=3200000 edges. fp32 in, fp32 out.
// d_out fp32 layout: [ result (NN) | out2 (NE,3) rows = [src,dst,val] ].
//
// Round-4 counters: edge kernel 336us, VALUBusy 1.5%, HBM 12.5%,
// WRITE_SIZE 237MB vs 38.8MB logical => ~6.4M fp32 atomics writing through
// to HBM (cross-XCD coherence). Fix: (1) factor the edge update so only
// conc[src] is gathered per edge:  A[s]+=val, B[d]+=val*conc[s], and
// node_new[n]=(B[n]-A[n]*conc[n])/size[n] at the end; (2) R-way (8) replica
// accumulators in d_ws selected by blockIdx&(R-1) so each accumulator line
// is touched by ~one XCD only (round-robin dispatch heuristic; correctness
// independent of mapping).

__device__ __forceinline__ float conv_val(const float* __restrict__ flow,
                                          long long e, const float* w) {
    const float4* fp = (const float4*)(flow + e * 12);
    float acc = w[36];
#pragma unroll
    for (int q = 0; q < 9; ++q) {
        float4 v = fp[q];
        acc = fmaf(v.x, w[q * 4 + 0], acc);
        acc = fmaf(v.y, w[q * 4 + 1], acc);
        acc = fmaf(v.z, w[q * 4 + 2], acc);
        acc = fmaf(v.w, w[q * 4 + 3], acc);
    }
    return acc;
}

// Kernel 1: conc[n] = od[n,15,0]  and zero the 2*R*NN replica accumulators.
// ws layout (floats): [ conc (NN) | A (R*NN) | B (R*NN) ]
__global__ __launch_bounds__(256) void prep(
    const float* __restrict__ od,
    float* __restrict__ ws,
    int n_nodes, int total)      // total = (1 + 2R) * NN
{
    int i = blockIdx.x * blockDim.x + threadIdx.x;
    if (i >= total) return;
    if (i < n_nodes) {
        ws[i] = od[(long long)i * 48 + 45];   // conc
    } else {
        ws[i] = 0.0f;                          // A/B replicas
    }
}

// Kernel 2: per-edge conv + out2 + factored atomic accumulation.
__global__ __launch_bounds__(256) void edge_kernel(
    const float* __restrict__ flow, const int* __restrict__ ei,
    const float* __restrict__ conv_w, const float* __restrict__ conv_b,
    const float* __restrict__ conc,
    float* __restrict__ A,          // R * NN
    float* __restrict__ B,          // R * NN
    float* __restrict__ out2,
    int n_edges, int n_nodes, int rep_mask)
{
    __shared__ float w[40];
    int t = threadIdx.x;
    if (t < 36) {
        int i  = t & 3;
        int kw = (t >> 2) % 3;
        int kh = t / 12;
        w[t] = conv_w[i * 9 + kh * 3 + kw];
    }
    if (t == 36) w[36] = conv_b[0];
    __syncthreads();

    int e = blockIdx.x * blockDim.x + t;
    if (e >= n_edges) return;

    float val = conv_val(flow, e, w);
    int s = ei[e];
    int d = ei[n_edges + e];

    float* o = out2 + (long long)e * 3;
    o[0] = (float)s; o[1] = (float)d; o[2] = val;

    if (s != d) {
        int rep = blockIdx.x & rep_mask;          // ~XCD-local replica
        long long off = (long long)rep * n_nodes;
        float cs = conc[s];
        atomicAdd(A + off + s, val);
        atomicAdd(B + off + d, val * cs);
    }
}

// Kernel 3: reduce replicas + compose result.
__global__ __launch_bounds__(256) void node_final(
    const float* __restrict__ od,
    const float* __restrict__ conc,
    const float* __restrict__ A,
    const float* __restrict__ B,
    float* __restrict__ out,
    int n_nodes, int n_rep)
{
    int n = blockIdx.x * blockDim.x + threadIdx.x;
    if (n >= n_nodes) return;

    float a = 0.0f, b = 0.0f;
    for (int r = 0; r < n_rep; ++r) {
        long long off = (long long)r * n_nodes + n;
        a += A[off];
        b += B[off];
    }

    long long base = (long long)n * 48 + 45;
    float c  = conc[n];
    float p  = od[base + 1];
    float is = 1.0f / od[base + 2];

    float res = c;
    if (n != n_nodes - 1)
        res += (b - a * c) * is + 0.0052f * p * is;
    out[n] = res;
}

extern "C" void kernel_launch(void* const* d_in, const int* in_sizes, int n_in,
                              void* d_out, int out_size, void* d_ws, size_t ws_size,
                              hipStream_t stream) {
    const float* od   = (const float*)d_in[0];
    const float* flow = (const float*)d_in[1];
    const float* cw   = (const float*)d_in[2];
    const float* cb   = (const float*)d_in[3];
    const int*   ei   = (const int*)d_in[4];

    const int n_nodes = in_sizes[0] / 48;
    const int n_edges = in_sizes[4] / 2;

    float* out_res = (float*)d_out;          // (NN,)
    float* out2    = out_res + n_nodes;      // (NE,3)

    // Pick replica count R in {8,4,2,1} that fits: (1 + 2R)*NN floats.
    int R = 8;
    while (R > 1 && ws_size < (size_t)(1 + 2 * R) * n_nodes * sizeof(float))
        R >>= 1;
    // ws_size >= 1.6MB is proven (round-4 Path A ran), so R >= 1 fits.

    float* ws   = (float*)d_ws;
    float* conc = ws;                           // NN
    float* A    = ws + (size_t)n_nodes;         // R*NN
    float* B    = A + (size_t)R * n_nodes;      // R*NN

    const int total = (1 + 2 * R) * n_nodes;

    dim3 blk(256);
    dim3 grid_prep((total + 255) / 256);
    dim3 grid_nodes((n_nodes + 255) / 256);
    dim3 grid_edges((n_edges + 255) / 256);

    prep<<<grid_prep, blk, 0, stream>>>(od, ws, n_nodes, total);
    edge_kernel<<<grid_edges, blk, 0, stream>>>(flow, ei, cw, cb, conc,
                                                A, B, out2,
                                                n_edges, n_nodes, R - 1);
    node_final<<<grid_nodes, blk, 0, stream>>>(od, conc, A, B, out_res,
                                               n_nodes, R);
}

// Round 6
// 365.115 us; speedup vs baseline: 1.4350x; 1.4000x over previous
//
#include <hip/hip_runtime.h>

// PINNLayer — NN=100000, NE=3200000. fp32 in, fp32 out.
// d_out fp32: [ result (NN) | out2 (NE,3) rows = [src,dst,val] ].
//
// Round-5 forensics: 6.4M random fp32 atomics cost a fixed ~31B/op memory-side
// RMW (WRITE_SIZE 237MB, byte-identical across layouts; ~20G ops/s) — replica
// locality is irrelevant. This version has ZERO random atomics:
//   P1 edge_conv: conv + write out2 (which doubles as the [s,d,val] record
//      staging buffer; 38.4MB, L3-resident for re-reads).
//   P2 accum: 13 node-windows x 16 record slices; LDS tables A[8192],B[8192];
//      flush once per (block,node) as ONE u64 fixed-point atomic packing
//      (a,b,cnt) -> ~1.6M atomics to CONSECUTIVE addresses (8/line).
//   P3 node_final: decode + compose.

#define WSHIFT 13
#define WSIZE  8192     // nodes per window (64KB LDS for two fp32 tables)
#define PB     16       // record slices (blocks per window)
#define FPS    8192.0f  // fixed-point scale 2^13
#define QBIAS  (1 << 20)
#define QCLMP  ((1 << 19) - 1)

// ---------------------------------------------------------------------------
__global__ __launch_bounds__(256) void prep(
    const float* __restrict__ od,
    float* __restrict__ conc,
    unsigned long long* __restrict__ acc,
    int n_nodes)
{
    int n = blockIdx.x * blockDim.x + threadIdx.x;
    if (n >= n_nodes) return;
    conc[n] = od[(long long)n * 48 + 45];   // origin_data[n,15,0]
    acc[n]  = 0ULL;
}

// ---------------------------------------------------------------------------
// P1: conv + out2 (no atomics, no gathers).
// val[e] = b + sum_{j<36} flow[e*12+j] * w_re[j],
//   w_re[kh*12+kw*4+i] = conv_w[i*9+kh*3+kw]
__global__ __launch_bounds__(256) void edge_conv(
    const float* __restrict__ flow, const int* __restrict__ ei,
    const float* __restrict__ conv_w, const float* __restrict__ conv_b,
    float* __restrict__ out2, int n_edges)
{
    __shared__ float w[40];
    int t = threadIdx.x;
    if (t < 36) {
        int i  = t & 3;
        int kw = (t >> 2) % 3;
        int kh = t / 12;
        w[t] = conv_w[i * 9 + kh * 3 + kw];
    }
    if (t == 36) w[36] = conv_b[0];
    __syncthreads();

    int e = blockIdx.x * blockDim.x + t;
    if (e >= n_edges) return;

    const float4* fp = (const float4*)(flow + (long long)e * 12);
    float acc = w[36];
#pragma unroll
    for (int q = 0; q < 9; ++q) {
        float4 v = fp[q];
        acc = fmaf(v.x, w[q * 4 + 0], acc);
        acc = fmaf(v.y, w[q * 4 + 1], acc);
        acc = fmaf(v.z, w[q * 4 + 2], acc);
        acc = fmaf(v.w, w[q * 4 + 3], acc);
    }

    float* o = out2 + (long long)e * 3;
    o[0] = (float)ei[e];
    o[1] = (float)ei[n_edges + e];
    o[2] = acc;
}

// ---------------------------------------------------------------------------
// P2: windowed LDS accumulation over the out2 records.
__global__ __launch_bounds__(1024) void accum(
    const float* __restrict__ out2,
    const float* __restrict__ conc,
    unsigned long long* __restrict__ acc,
    int n_edges, int n_nodes)
{
    __shared__ float tA[WSIZE];
    __shared__ float tB[WSIZE];

    const int w    = blockIdx.x / PB;     // window id
    const int sl   = blockIdx.x % PB;     // record slice
    const int base = w << WSHIFT;

    for (int i = threadIdx.x; i < WSIZE; i += 1024) { tA[i] = 0.f; tB[i] = 0.f; }
    __syncthreads();

    const long long e0 = (long long)sl * n_edges / PB;
    const long long e1 = (long long)(sl + 1) * n_edges / PB;
    for (long long e = e0 + threadIdx.x; e < e1; e += 1024) {
        const float* r = out2 + e * 3;
        float fs = r[0], fd = r[1], v = r[2];
        int s = (int)fs, d = (int)fd;
        if (s == d) continue;
        if ((s >> WSHIFT) == w) atomicAdd(&tA[s - base], v);
        if ((d >> WSHIFT) == w) atomicAdd(&tB[d - base], v * conc[s]);
    }
    __syncthreads();

    // Flush: one u64 fixed-point atomic per touched node, consecutive addrs.
    for (int i = threadIdx.x; i < WSIZE; i += 1024) {
        int n = base + i;
        if (n >= n_nodes) continue;
        float a = tA[i], b = tB[i];
        if (a == 0.f && b == 0.f) continue;
        int qa = __float2int_rn(a * FPS);
        int qb = __float2int_rn(b * FPS);
        qa = min(max(qa, -QCLMP), QCLMP);
        qb = min(max(qb, -QCLMP), QCLMP);
        unsigned long long enc =
            ((unsigned long long)(unsigned)(qa + QBIAS) << 37) +
            ((unsigned long long)(unsigned)(qb + QBIAS) << 10) + 1ULL;
        atomicAdd(acc + n, enc);
    }
}

// ---------------------------------------------------------------------------
// P3: decode (a,b,cnt) and compose result.
__global__ __launch_bounds__(256) void node_final(
    const float* __restrict__ od,
    const float* __restrict__ conc,
    const unsigned long long* __restrict__ acc,
    float* __restrict__ out, int n_nodes)
{
    int n = blockIdx.x * blockDim.x + threadIdx.x;
    if (n >= n_nodes) return;

    unsigned long long t = acc[n];
    long long cnt = (long long)(t & 1023ULL);
    unsigned long long t2 = t >> 10;
    long long sbr = (long long)(t2 & ((1ULL << 27) - 1));
    long long sar = (long long)(t2 >> 27);
    float a = (float)(sar - cnt * QBIAS) * (1.0f / FPS);
    float b = (float)(sbr - cnt * QBIAS) * (1.0f / FPS);

    long long bi = (long long)n * 48 + 45;
    float c  = conc[n];
    float p  = od[bi + 1];
    float is = 1.0f / od[bi + 2];

    float r = c;
    if (n != n_nodes - 1)
        r += (b - a * c) * is + 0.0052f * p * is;
    out[n] = r;
}

// ---------------------------------------------------------------------------
extern "C" void kernel_launch(void* const* d_in, const int* in_sizes, int n_in,
                              void* d_out, int out_size, void* d_ws, size_t ws_size,
                              hipStream_t stream) {
    const float* od   = (const float*)d_in[0];
    const float* flow = (const float*)d_in[1];
    const float* cw   = (const float*)d_in[2];
    const float* cb   = (const float*)d_in[3];
    const int*   ei   = (const int*)d_in[4];

    const int n_nodes = in_sizes[0] / 48;
    const int n_edges = in_sizes[4] / 2;

    float* out_res = (float*)d_out;        // (NN,)
    float* out2    = out_res + n_nodes;    // (NE,3) — also the record staging

    float* conc = (float*)d_ws;                                   // NN fp32
    unsigned long long* acc =
        (unsigned long long*)((char*)d_ws + ((size_t)n_nodes * 4 + 7) / 8 * 8);

    const int n_win = (n_nodes + WSIZE - 1) >> WSHIFT;            // 13

    dim3 blk(256);
    dim3 grid_nodes((n_nodes + 255) / 256);
    dim3 grid_edges((n_edges + 255) / 256);

    prep<<<grid_nodes, blk, 0, stream>>>(od, conc, acc, n_nodes);
    edge_conv<<<grid_edges, blk, 0, stream>>>(flow, ei, cw, cb, out2, n_edges);
    accum<<<dim3(n_win * PB), dim3(1024), 0, stream>>>(out2, conc, acc,
                                                       n_edges, n_nodes);
    node_final<<<grid_nodes, blk, 0, stream>>>(od, conc, acc, out_res, n_nodes);
}